// Round 14
// baseline (78.895 us; speedup 1.0000x reference)
//
#include <hip/hip_runtime.h>
#include <hip/hip_bf16.h>

#define BB 4
#define NN 4096
#define MM 4096
#define CC 256
#define CAP 128
#define NBIN 384
#define NCH 16
#define CHK 256

typedef __attribute__((ext_vector_type(8))) short bf16x8;
typedef __attribute__((ext_vector_type(4))) float f32x4;

static __device__ __forceinline__ float bf2f(unsigned short u) {
    return __uint_as_float(((unsigned)u) << 16);
}
static __device__ __forceinline__ unsigned short f2bf(float f) {
    unsigned u = __float_as_uint(f);
    u += 0x7fffu + ((u >> 16) & 1u);   // round-to-nearest-even
    return (unsigned short)(u >> 16);
}
static __device__ __forceinline__ bf16x8 asbf(uint4 u) {
    union { uint4 a; bf16x8 b; } c; c.a = u; return c.b;
}
// async global->LDS, 16B per lane; LDS dest wave-uniform base + lane*16B
static __device__ __forceinline__ void gload16(const unsigned short* g, unsigned short* l) {
    __builtin_amdgcn_global_load_lds(
        (const __attribute__((address_space(1))) unsigned int*)g,
        (__attribute__((address_space(3))) unsigned int*)l, 16, 0, 0);
}

// ================= fused prep (slim): W pack / bin counts / urmean / Vsum0 ====
// y 0-3: W fp32->bf16 packed  Wpk[w][kk][t][lane][j]
// y 4  : bin_count R (x<64);  y 5: bin_count L (x<64)
// y 6  : x<4 urmean(b=x); x==4 Vsum zero
__global__ __launch_bounds__(256) void prep_kernel(
    const float* __restrict__ Wq, const float* __restrict__ Wk,
    const float* __restrict__ Wv, const float* __restrict__ Wm,
    const float* __restrict__ kptsR, const float* __restrict__ kptsL,
    unsigned short* __restrict__ Wpk,
    int* __restrict__ hist, unsigned short* __restrict__ prank,
    int* __restrict__ histL, unsigned short* __restrict__ prankL,
    float* __restrict__ Vsum, float* __restrict__ Usum)
{
    __shared__ __align__(16) unsigned char SMEM[2048];
    const int tid = threadIdx.x, y = blockIdx.y, x = blockIdx.x;

    if (y < 4) {                                   // ---- W pack
        const float* S = (y == 0) ? Wq : (y == 1) ? Wk : (y == 2) ? Wv : Wm;
        int o = x * 256 + tid;
        int j = o & 7, lane = (o >> 3) & 63, kt = o >> 9;
        int kk = kt >> 4, t = kt & 15;
        int r = t * 16 + (lane & 15), c = kk * 32 + (lane >> 4) * 8 + j;
        Wpk[(size_t)y * 65536 + o] = f2bf(S[r * 256 + c]);
        return;
    }
    if (y == 4 || y == 5) {                        // ---- bin_count (R or L)
        if (x >= NCH * BB) return;
        __shared__ int h[NBIN];
        __shared__ short sbin[CHK];
        const float* KP = (y == 5) ? kptsL : kptsR;
        int* H = (y == 5) ? histL : hist;
        unsigned short* PR = (y == 5) ? prankL : prank;
        int chunk = x & 15, b = x >> 4;
        for (int i = tid; i < NBIN; i += CHK) h[i] = 0;
        int m = chunk * CHK + tid;
        float2 p = ((const float2*)KP)[(size_t)b * MM + m];
        int bin = (int)p.y;
        sbin[tid] = (short)bin;
        __syncthreads();
        atomicAdd(&h[bin], 1);
        int r = 0;
        for (int t = 0; t < tid; ++t) r += (sbin[t] == bin);
        PR[(b << 12) + m] = (unsigned short)r;
        __syncthreads();
        for (int i = tid; i < NBIN; i += CHK)
            H[((size_t)b * NCH + chunk) * NBIN + i] = h[i];
        return;
    }
    // ---- y == 6: urmean (x<4) / Vsum zero (x==4)
    if (x < BB) {
        int b = x;
        float s = 0.f;
        for (int m = tid; m < MM; m += 256) s += kptsR[((size_t)b * MM + m) * 2 + 0];
#pragma unroll
        for (int off = 32; off; off >>= 1) s += __shfl_xor(s, off);
        float* sr = (float*)SMEM;
        int wave = tid >> 6, lane = tid & 63;
        if (lane == 0) sr[wave] = s;
        __syncthreads();
        if (tid == 0) Usum[b] = sr[0] + sr[1] + sr[2] + sr[3];
    } else if (x == BB) {
        for (int i = tid; i < BB * CC; i += 256) Vsum[i] = 0.f;
    }
}

// ================= QKV projection (fp32 A in-kernel pack) + bin place =========
// y=0..2: O = A @ W^T + b, A fp32 [16384][256]. Block = 64 rows x 64 cols,
// 4 waves x 16 rows. A-tile staged fp32->bf16 XOR-swizzled in LDS (32 KB);
// W panel (32 KB) via global_load_lds. k-loop: 1 A ds_read + 4 W ds_reads +
// 4 MFMA per kk, no barriers. XCD remap: same rows -> same XCD across colgroups.
// y==3 (x<128): parallel bin place (R: x<64 writes binStart+UV; L: x>=64).
__global__ __launch_bounds__(256, 2) void qkv_mfma_kernel(
    const float* __restrict__ A0, const float* __restrict__ A1,
    const float* __restrict__ A2, const unsigned short* __restrict__ Wpk,
    const float* __restrict__ b0, const float* __restrict__ b1, const float* __restrict__ b2,
    unsigned short* __restrict__ O0, unsigned short* __restrict__ O1,
    unsigned short* __restrict__ O2, float* __restrict__ Vsum,
    const int* __restrict__ hist, const int* __restrict__ histL,
    int* __restrict__ binStart,
    const float* __restrict__ kptsR, const float* __restrict__ kptsL,
    const unsigned short* __restrict__ prank, const unsigned short* __restrict__ prankL,
    unsigned short* __restrict__ sortedM, float2* __restrict__ sortedUV,
    unsigned short* __restrict__ sortedNL)
{
    __shared__ __align__(16) unsigned char SMEM[65536];   // A 32KB | W 32KB
    const int tid = threadIdx.x, wid = tid >> 6, lane = tid & 63;
    const int y = blockIdx.y;

    if (y == 3) {                  // ---- place with local scan (128 parallel blocks)
        if (blockIdx.x >= 2 * NCH * BB) return;
        const int isL = blockIdx.x >= NCH * BB;
        const int xx = blockIdx.x & (NCH * BB - 1);
        const int b = xx >> 4, chunk = xx & 15;
        const int* H = isL ? histL : hist;
        int* h2 = (int*)SMEM;                      // [NCH][NBIN] 24576 B
        int* sc = (int*)(SMEM + 24576);            // [NBIN]
        for (int i = tid; i < NCH * NBIN; i += 256)
            h2[i] = H[(size_t)b * NCH * NBIN + i];
        __syncthreads();
        for (int v = tid; v < NBIN; v += 256) {
            int tot = 0;
#pragma unroll
            for (int c = 0; c < NCH; ++c) tot += h2[c * NBIN + v];
            sc[v] = tot;
        }
        __syncthreads();
        for (int off = 1; off < NBIN; off <<= 1) {
            int v1 = tid + 256;
            int t0 = (tid >= off) ? sc[tid - off] : 0;
            int t1 = (v1 < NBIN && v1 >= off) ? sc[v1 - off] : 0;
            __syncthreads();
            sc[tid] += t0;
            if (v1 < NBIN) sc[v1] += t1;
            __syncthreads();
        }
        if (!isL && chunk == 0) {
            for (int v = tid; v < NBIN; v += 256)
                binStart[b * (NBIN + 1) + v] = v ? sc[v - 1] : 0;
            if (tid == 0) binStart[b * (NBIN + 1) + NBIN] = sc[NBIN - 1];
        }
        int m = chunk * CHK + tid;
        float2 p = ((const float2*)(isL ? kptsL : kptsR))[(size_t)b * MM + m];
        int bin = (int)p.y;
        int ex = bin ? sc[bin - 1] : 0;
        for (int c = 0; c < chunk; ++c) ex += h2[c * NBIN + bin];
        int pos = ex + (isL ? prankL : prank)[(b << 12) + m];
        if (isL) {
            sortedNL[(b << 12) + pos] = (unsigned short)m;
        } else {
            sortedM[(b << 12) + pos] = (unsigned short)m;
            sortedUV[(b << 12) + pos] = p;
        }
        return;
    }

    const int lrow = lane & 15, lk = lane >> 4;
    const float* A = (y == 0) ? A0 : (y == 1) ? A1 : A2;
    const float* bias = (y == 0) ? b0 : (y == 1) ? b1 : b2;
    unsigned short* Out = (y == 0) ? O0 : (y == 1) ? O1 : O2;
    const unsigned short* W = Wpk + (size_t)y * 65536;

    const int bid = blockIdx.x;
    const int g = (bid >> 3) & 3;                    // colgroup (64 cols)
    const int rblk = (bid & 7) + ((bid >> 5) << 3);  // [0,256): same rblk -> same XCD
    const size_t rbase = (size_t)rblk * 64;

    unsigned short* Al = (unsigned short*)SMEM;            // 32 KB, swizzled
    unsigned short* Wl = (unsigned short*)(SMEM + 32768);  // 32 KB, linear

    // issue W panel loads first (latency overlaps A staging)
#pragma unroll
    for (int i = 0; i < 8; ++i) {
        int kk = wid * 2 + (i >> 2), q = i & 3;
        gload16(W + (size_t)kk * 8192 + g * 2048 + q * 512 + lane * 8,
                Wl + kk * 2048 + q * 512 + lane * 8);
    }

    // stage A-tile: 64 rows fp32 -> bf16, XOR-swizzled (8-elem granule)
    const float* Af = A + rbase * CC;
#pragma unroll
    for (int it = 0; it < 16; ++it) {
        int row = it * 4 + wid;
        float4 f = *(const float4*)(Af + row * 256 + lane * 4);
        ushort4 h = make_ushort4(f2bf(f.x), f2bf(f.y), f2bf(f.z), f2bf(f.w));
        *(ushort4*)&Al[row * 256 + ((lane * 4) ^ ((row & 7) << 3))] = h;
    }

    f32x4 acc[4];
#pragma unroll
    for (int t = 0; t < 4; ++t) acc[t] = (f32x4){0.f, 0.f, 0.f, 0.f};

    asm volatile("s_waitcnt vmcnt(0)" ::: "memory");
    __syncthreads();                                 // A + W resident

    const int arow = wid * 16 + lrow;
    const int xr = (arow & 7) << 3;
#pragma unroll
    for (int kk = 0; kk < 8; ++kk) {
        bf16x8 a = *(const bf16x8*)&Al[arow * 256 + ((kk * 32 + lk * 8) ^ xr)];
#pragma unroll
        for (int t = 0; t < 4; ++t) {
            bf16x8 wf = *(const bf16x8*)&Wl[kk * 2048 + t * 512 + lane * 8];
            acc[t] = __builtin_amdgcn_mfma_f32_16x16x32_bf16(a, wf, acc[t], 0, 0, 0);
        }
    }

    // V column sums for the all-masked fallback path (y==2 only)
    if (y == 2) {
#pragma unroll
        for (int t = 0; t < 4; ++t) {
            int col = g * 64 + t * 16 + lrow;
            float vs = acc[t][0] + acc[t][1] + acc[t][2] + acc[t][3];
            vs += __shfl_xor(vs, 16);
            vs += __shfl_xor(vs, 32);
            if (lk == 0)
                atomicAdd(&Vsum[(rblk >> 6) * CC + col], vs + 16.f * bias[col]);
        }
    }

    __syncthreads();                                 // done reading Al; reuse as bounce
    unsigned short* Bo = (unsigned short*)SMEM;      // [64][64]
#pragma unroll
    for (int t = 0; t < 4; ++t) {
        float bb = bias[g * 64 + t * 16 + lrow];
#pragma unroll
        for (int rr = 0; rr < 4; ++rr) {
            int row = wid * 16 + lk * 4 + rr;
            Bo[row * 64 + t * 16 + lrow] = f2bf(acc[t][rr] + bb);
        }
    }
    __syncthreads();
#pragma unroll
    for (int it = 0; it < 2; ++it) {
        int idx = it * 2048 + tid * 8;
        int row = idx >> 6, col = idx & 63;
        *(uint4*)(Out + (rbase + row) * CC + g * 64 + col) = *(const uint4*)&Bo[idx];
    }
}

// ================= MFMA projection for out0 (A pre-packed bf16) ===============
// wave = 32 rows x 64 cols, block = 128 rows x 64 cols, W panel in LDS once.
__global__ __launch_bounds__(256, 4) void proj_mfma_kernel(
    const unsigned short* __restrict__ A, const unsigned short* __restrict__ Wpk,
    const float* __restrict__ bias, float* __restrict__ Out)
{
    __shared__ __align__(16) unsigned char SMEM[32768];   // W panel / bounce
    const int tid = threadIdx.x, wid = tid >> 6, lane = tid & 63;
    const int lrow = lane & 15, lk = lane >> 4;

    const int bid = blockIdx.x;
    const int g = (bid >> 3) & 3;                    // colgroup (64 cols)
    const int rblk = (bid & 7) + ((bid >> 5) << 3);  // [0,128)
    const size_t rbase = (size_t)rblk * 128;
    const int rt0 = rblk * 8 + wid * 2;

    unsigned short* Wl = (unsigned short*)SMEM;
#pragma unroll
    for (int i = 0; i < 8; ++i) {
        int kk = wid * 2 + (i >> 2), q = i & 3;
        gload16(Wpk + (size_t)kk * 8192 + g * 2048 + q * 512 + lane * 8,
                Wl + kk * 2048 + q * 512 + lane * 8);
    }

    const unsigned short* Ap = A + (size_t)rt0 * 4096 + lane * 8;
    uint4 a[2][2];
    a[0][0] = *(const uint4*)(Ap);
    a[0][1] = *(const uint4*)(Ap + 4096);

    f32x4 acc[4][2];
#pragma unroll
    for (int t = 0; t < 4; ++t) {
        acc[t][0] = (f32x4){0.f, 0.f, 0.f, 0.f};
        acc[t][1] = (f32x4){0.f, 0.f, 0.f, 0.f};
    }

    asm volatile("s_waitcnt vmcnt(0)" ::: "memory");
    __syncthreads();                                 // W panel resident

#pragma unroll
    for (int kk = 0; kk < 8; ++kk) {
        const int cur = kk & 1, nxt = cur ^ 1;
        if (kk < 7) {
            a[nxt][0] = *(const uint4*)(Ap + (kk + 1) * 512);
            a[nxt][1] = *(const uint4*)(Ap + 4096 + (kk + 1) * 512);
        }
        bf16x8 af0 = asbf(a[cur][0]);
        bf16x8 af1 = asbf(a[cur][1]);
#pragma unroll
        for (int t = 0; t < 4; ++t) {
            bf16x8 wf = *(const bf16x8*)(Wl + kk * 2048 + t * 512 + lane * 8);
            acc[t][0] = __builtin_amdgcn_mfma_f32_16x16x32_bf16(af0, wf, acc[t][0], 0, 0, 0);
            acc[t][1] = __builtin_amdgcn_mfma_f32_16x16x32_bf16(af1, wf, acc[t][1], 0, 0, 0);
        }
    }

    __syncthreads();                                 // done reading Wl; reuse as bounce
    float* Bo = (float*)SMEM;                        // [128][64] halves
#pragma unroll
    for (int half = 0; half < 2; ++half) {
#pragma unroll
        for (int t = 0; t < 4; ++t) {
            float bb = bias[g * 64 + t * 16 + lrow];
#pragma unroll
            for (int rr = 0; rr < 4; ++rr) {
                int row = wid * 32 + half * 16 + lk * 4 + rr;
                if ((row >> 6) == half)
                    Bo[(row & 63) * 64 + t * 16 + lrow] = acc[t][half][rr] + bb;
            }
        }
        __syncthreads();
        // NOTE: rows wid*32+half*16+... span both halves; simpler: write all then copy
        __syncthreads();
    }
    // simpler correct path: recompute epilogue without halving — direct store
#pragma unroll
    for (int t = 0; t < 4; ++t) {
        float bb = bias[g * 64 + t * 16 + lrow];
#pragma unroll
        for (int s = 0; s < 2; ++s)
#pragma unroll
            for (int rr = 0; rr < 4; ++rr) {
                int row = wid * 32 + s * 16 + lk * 4 + rr;
                Out[(rbase + row) * CC + g * 64 + t * 16 + lrow] = acc[t][s][rr] + bb;
            }
    }
}

// packed-MT write offset for row bn, cols lane*4..lane*4+3
static __device__ __forceinline__ size_t mt_po(int bn, int lane) {
    return ((size_t)(bn >> 4)) * 4096 + (size_t)(lane >> 3) * 512
         + (size_t)(((lane >> 1) & 3) * 16 + (bn & 15)) * 8 + (lane & 1) * 4;
}

// ================= sparse attention: one wave per query row (vL-sorted) =======
__global__ __launch_bounds__(256) void attn_kernel(
    const unsigned short* __restrict__ Q, const unsigned short* __restrict__ K,
    const unsigned short* __restrict__ V,
    const float* __restrict__ kptsL, const unsigned short* __restrict__ sortedNL,
    const int* __restrict__ binStart, const unsigned short* __restrict__ sortedM,
    const float2* __restrict__ sortedUV,
    const float* __restrict__ Vsum, const float* __restrict__ Usum,
    unsigned short* __restrict__ Mpk, float* __restrict__ out1, float* __restrict__ out2)
{
    __shared__ unsigned short s_m[4][CAP];
    __shared__ float s_du[4][CAP];
    __shared__ float s_p[4][CAP];

    const int wid = threadIdx.x >> 6, lane = threadIdx.x & 63;
    const int bid = (blockIdx.x & 7) * 512 + (blockIdx.x >> 3);
    const int si = bid * 4 + wid;          // global sorted index
    const int b = si >> 12;
    const int bn = (b << 12) + sortedNL[si];

    const int gi = lane >> 4, c = lane & 15;
    float qf[16];
    {
        const unsigned short* Qr = Q + (size_t)bn * CC + c * 16;
#pragma unroll
        for (int j = 0; j < 4; ++j) {
            ushort4 t = *(const ushort4*)(Qr + j * 4);
            qf[j * 4 + 0] = bf2f(t.x); qf[j * 4 + 1] = bf2f(t.y);
            qf[j * 4 + 2] = bf2f(t.z); qf[j * 4 + 3] = bf2f(t.w);
        }
    }

    float2 kl = *(const float2*)(kptsL + (size_t)bn * 2);
    float uL = kl.x, vL = kl.y;

    int ifl = (int)vL;
    int v0 = max(0, ifl - 3), v1 = min(NBIN - 1, ifl + 3);
    int s = binStart[b * (NBIN + 1) + v0];
    int e = binStart[b * (NBIN + 1) + v1 + 1];

    int cnt = 0;
    for (int i0 = s; i0 < e; i0 += 64) {
        int i = i0 + lane;
        bool valid = false;
        float du = 0.f;
        int m = 0;
        if (i < e) {
            float2 uv = sortedUV[(b << 12) + i];
            m = sortedM[(b << 12) + i];
            du = uL - uv.x;
            float dv = fabsf(vL - uv.y);
            valid = (dv < 3.0f) && (du > 0.0f) && (du < 192.0f);
        }
        unsigned long long bal = __ballot(valid);
        int pos = cnt + __popcll(bal & ((1ull << lane) - 1ull));
        if (valid && pos < CAP) { s_m[wid][pos] = (unsigned short)m; s_du[wid][pos] = du; }
        cnt += __popcll(bal);
    }
    if (cnt > CAP) cnt = CAP;

    if (cnt == 0) {
        float4 vs = *(const float4*)(Vsum + b * CC + lane * 4);
        ushort4 o = make_ushort4(f2bf(vs.x * (1.f / MM)), f2bf(vs.y * (1.f / MM)),
                                 f2bf(vs.z * (1.f / MM)), f2bf(vs.w * (1.f / MM)));
        *(ushort4*)(Mpk + mt_po(bn, lane)) = o;
        if (lane == 0) { out1[bn] = uL - Usum[b] * (1.f / MM); out2[bn] = 0.f; }
        return;
    }

    const unsigned short* Kb = K + (((size_t)b) << 12) * CC;
    for (int i0 = 0; i0 < cnt; i0 += 4) {
        int i = i0 + gi;
        int m = s_m[wid][(i < cnt) ? i : 0];
        const unsigned short* Kr = Kb + (size_t)m * CC + c * 16;
        float d = 0.f;
#pragma unroll
        for (int j = 0; j < 4; ++j) {
            ushort4 t = *(const ushort4*)(Kr + j * 4);
            d += qf[j * 4 + 0] * bf2f(t.x) + qf[j * 4 + 1] * bf2f(t.y)
               + qf[j * 4 + 2] * bf2f(t.z) + qf[j * 4 + 3] * bf2f(t.w);
        }
        d += __shfl_xor(d, 8); d += __shfl_xor(d, 4);
        d += __shfl_xor(d, 2); d += __shfl_xor(d, 1);
        if (c == 0 && i < cnt) s_p[wid][i] = d;
    }

    const float NEG = -3.0e38f;
    float mx, ps, ds, inv;
    if (cnt <= 64) {
        float x0 = (lane < cnt) ? s_p[wid][lane] * 0.0625f : NEG;
        mx = x0;
#pragma unroll
        for (int off = 32; off; off >>= 1) mx = fmaxf(mx, __shfl_xor(mx, off));
        float p0 = (lane < cnt) ? __expf(x0 - mx) : 0.f;
        float d0 = (lane < cnt) ? s_du[wid][lane] : 0.f;
        ps = p0; ds = p0 * d0;
#pragma unroll
        for (int off = 32; off; off >>= 1) { ps += __shfl_xor(ps, off); ds += __shfl_xor(ds, off); }
        inv = 1.f / ps;
        if (lane < cnt) s_p[wid][lane] = p0 * inv;
    } else {
        float x0 = (lane < cnt) ? s_p[wid][lane] * 0.0625f : NEG;
        float x1 = (lane + 64 < cnt) ? s_p[wid][lane + 64] * 0.0625f : NEG;
        mx = fmaxf(x0, x1);
#pragma unroll
        for (int off = 32; off; off >>= 1) mx = fmaxf(mx, __shfl_xor(mx, off));
        float p0 = (lane < cnt) ? __expf(x0 - mx) : 0.f;
        float p1 = (lane + 64 < cnt) ? __expf(x1 - mx) : 0.f;
        float d0 = (lane < cnt) ? s_du[wid][lane] : 0.f;
        float d1 = (lane + 64 < cnt) ? s_du[wid][lane + 64] : 0.f;
        ps = p0 + p1; ds = p0 * d0 + p1 * d1;
#pragma unroll
        for (int off = 32; off; off >>= 1) { ps += __shfl_xor(ps, off); ds += __shfl_xor(ds, off); }
        inv = 1.f / ps;
        if (lane < cnt) s_p[wid][lane] = p0 * inv;
        if (lane + 64 < cnt) s_p[wid][lane + 64] = p1 * inv;
    }

    const unsigned short* Vb = V + (((size_t)b) << 12) * CC;
    float a0 = 0.f, a1 = 0.f, a2 = 0.f, a3 = 0.f;
    float e0 = 0.f, e1 = 0.f, e2 = 0.f, e3 = 0.f;
    int i = 0;
    for (; i + 1 < cnt; i += 2) {
        float w0 = s_p[wid][i], w1 = s_p[wid][i + 1];
        ushort4 va = *(const ushort4*)(Vb + (size_t)s_m[wid][i] * CC + lane * 4);
        ushort4 vb = *(const ushort4*)(Vb + (size_t)s_m[wid][i + 1] * CC + lane * 4);
        a0 += w0 * bf2f(va.x); a1 += w0 * bf2f(va.y);
        a2 += w0 * bf2f(va.z); a3 += w0 * bf2f(va.w);
        e0 += w1 * bf2f(vb.x); e1 += w1 * bf2f(vb.y);
        e2 += w1 * bf2f(vb.z); e3 += w1 * bf2f(vb.w);
    }
    if (i < cnt) {
        float w0 = s_p[wid][i];
        ushort4 va = *(const ushort4*)(Vb + (size_t)s_m[wid][i] * CC + lane * 4);
        a0 += w0 * bf2f(va.x); a1 += w0 * bf2f(va.y);
        a2 += w0 * bf2f(va.z); a3 += w0 * bf2f(va.w);
    }
    ushort4 o = make_ushort4(f2bf(a0 + e0), f2bf(a1 + e1), f2bf(a2 + e2), f2bf(a3 + e3));
    *(ushort4*)(Mpk + mt_po(bn, lane)) = o;
    if (lane == 0) { out1[bn] = ds * inv; out2[bn] = 1.f; }
}

extern "C" void kernel_launch(void* const* d_in, const int* in_sizes, int n_in,
                              void* d_out, int out_size, void* d_ws, size_t ws_size,
                              hipStream_t stream) {
    const float* nodes_L = (const float*)d_in[0];
    const float* nodes_R = (const float*)d_in[1];
    const float* kpts_L  = (const float*)d_in[2];
    const float* kpts_R  = (const float*)d_in[3];
    const float* Wq = (const float*)d_in[4];
    const float* bq = (const float*)d_in[5];
    const float* Wk = (const float*)d_in[6];
    const float* bk = (const float*)d_in[7];
    const float* Wv = (const float*)d_in[8];
    const float* bv = (const float*)d_in[9];
    const float* Wm = (const float*)d_in[10];
    const float* bm = (const float*)d_in[11];

    char* ws = (char*)d_ws;
    unsigned short* Wpk = (unsigned short*)ws; ws += (size_t)4 * 65536 * 2;
    unsigned short* Qp  = (unsigned short*)ws; ws += (size_t)BB * NN * CC * 2;
    unsigned short* Kp  = (unsigned short*)ws; ws += (size_t)BB * MM * CC * 2;
    unsigned short* Vp  = (unsigned short*)ws; ws += (size_t)BB * MM * CC * 2;
    unsigned short* Mpk = (unsigned short*)ws; ws += (size_t)BB * NN * CC * 2;
    float* Vsum = (float*)ws;        ws += (size_t)BB * CC * 4;
    float* Usum = (float*)ws;        ws += (size_t)BB * 4;
    float2* sortedUV = (float2*)ws;  ws += (size_t)BB * MM * 8;
    int* binStart = (int*)ws;        ws += (size_t)BB * (NBIN + 1) * 4;
    unsigned short* sortedM = (unsigned short*)ws; ws += (size_t)BB * MM * 2;
    int* hist = (int*)ws;            ws += (size_t)BB * NCH * NBIN * 4;
    unsigned short* prank = (unsigned short*)ws;   ws += (size_t)BB * MM * 2;
    int* histL = (int*)ws;           ws += (size_t)BB * NCH * NBIN * 4;
    unsigned short* prankL = (unsigned short*)ws;  ws += (size_t)BB * NN * 2;
    unsigned short* sortedNL = (unsigned short*)ws;

    float* out0 = (float*)d_out;
    float* out1 = out0 + (size_t)BB * NN * CC;
    float* out2 = out1 + (size_t)BB * NN;

    // 1) slim prep: W pack + bin counts + urmean + Vsum zero
    prep_kernel<<<dim3(256, 7), dim3(256), 0, stream>>>(
        Wq, Wk, Wv, Wm, kpts_R, kpts_L,
        Wpk, hist, prank, histL, prankL, Vsum, Usum);

    // 2) fused Q/K/V projections with in-kernel fp32->bf16 pack (y=0..2)
    //    + parallel bin place R & L (y=3, x<128)
    qkv_mfma_kernel<<<dim3(1024, 4), dim3(256), 0, stream>>>(
        nodes_L, nodes_R, nodes_R, Wpk, bq, bk, bv, Qp, Kp, Vp, Vsum,
        hist, histL, binStart, kpts_R, kpts_L, prank, prankL,
        sortedM, sortedUV, sortedNL);

    // 3) sparse attention in vL-sorted order (writes Mpk packed)
    attn_kernel<<<dim3(BB * NN / 4), dim3(256), 0, stream>>>(
        Qp, Kp, Vp, kpts_L, sortedNL, binStart, sortedM, sortedUV,
        Vsum, Usum, Mpk, out1, out2);

    // 4) final projection: out0 = Mpk @ Wm^T + bm (fp32 out)
    proj_mfma_kernel<<<dim3(512, 1), dim3(256), 0, stream>>>(
        Mpk, Wpk + 3 * 65536, bm, out0);
}

// Round 15
// 60.254 us; speedup vs baseline: 1.3094x; 1.3094x over previous
//
#include <hip/hip_runtime.h>
#include <hip/hip_bf16.h>

#define BB 4
#define NN 4096
#define MM 4096
#define CC 256
#define CAP 128
#define NBIN 384
#define NCH 16
#define CHK 256

typedef __attribute__((ext_vector_type(8))) short bf16x8;
typedef __attribute__((ext_vector_type(4))) float f32x4;

static __device__ __forceinline__ float bf2f(unsigned short u) {
    return __uint_as_float(((unsigned)u) << 16);
}
static __device__ __forceinline__ unsigned short f2bf(float f) {
    unsigned u = __float_as_uint(f);
    u += 0x7fffu + ((u >> 16) & 1u);   // round-to-nearest-even
    return (unsigned short)(u >> 16);
}
static __device__ __forceinline__ bf16x8 asbf(uint4 u) {
    union { uint4 a; bf16x8 b; } c; c.a = u; return c.b;
}
// async global->LDS, 16B per lane; LDS dest wave-uniform base + lane*16B
static __device__ __forceinline__ void gload16(const unsigned short* g, unsigned short* l) {
    __builtin_amdgcn_global_load_lds(
        (const __attribute__((address_space(1))) unsigned int*)g,
        (__attribute__((address_space(3))) unsigned int*)l, 16, 0, 0);
}

// ================= fused prep ==================================================
// y 0-3: W fp32->bf16 packed; y 4-5: A fp32->bf16 packed; y 6: bin_count R;
// y 7: urmean / Vsum zero; y 8: bin_count L (query v-sort).
__global__ __launch_bounds__(256) void prep_kernel(
    const float* __restrict__ Wq, const float* __restrict__ Wk,
    const float* __restrict__ Wv, const float* __restrict__ Wm,
    const float* __restrict__ L, const float* __restrict__ R,
    const float* __restrict__ kptsR, const float* __restrict__ kptsL,
    unsigned short* __restrict__ Wpk, unsigned short* __restrict__ Lpk,
    unsigned short* __restrict__ Rpk,
    int* __restrict__ hist, unsigned short* __restrict__ prank,
    int* __restrict__ histL, unsigned short* __restrict__ prankL,
    float* __restrict__ Vsum, float* __restrict__ Usum)
{
    __shared__ __align__(16) unsigned char SMEM[32768];
    const int tid = threadIdx.x, y = blockIdx.y, x = blockIdx.x;

    if (y < 4) {                                   // ---- W pack
        const float* S = (y == 0) ? Wq : (y == 1) ? Wk : (y == 2) ? Wv : Wm;
        int o = x * 256 + tid;
        int j = o & 7, lane = (o >> 3) & 63, kt = o >> 9;
        int kk = kt >> 4, t = kt & 15;
        int r = t * 16 + (lane & 15), c = kk * 32 + (lane >> 4) * 8 + j;
        Wpk[(size_t)y * 65536 + o] = f2bf(S[r * 256 + c]);
        return;
    }
    if (y < 6) {                                   // ---- A pack (64 rows/block)
        const float* S = (y == 5) ? R : L;
        unsigned short* D = (y == 5) ? Rpk : Lpk;
        unsigned short* T = (unsigned short*)SMEM;
        const int wid = tid >> 6, lane = tid & 63;
        const size_t R0 = (size_t)x * 64;
#pragma unroll
        for (int it = 0; it < 16; ++it) {
            int row = it * 4 + wid;
            float4 f = *(const float4*)(S + (R0 + row) * 256 + lane * 4);
            ushort4 h = make_ushort4(f2bf(f.x), f2bf(f.y), f2bf(f.z), f2bf(f.w));
            int col = lane * 4;
            *(ushort4*)&T[row * 256 + (col ^ ((row & 7) << 3))] = h;
        }
        __syncthreads();
        unsigned short* Dp = D + (size_t)x * 16384;
#pragma unroll
        for (int p = 0; p < 8; ++p) {
            int u = p * 2048 + tid * 8;
            int rt = u >> 12, rem = u & 4095;
            int kk = rem >> 9, ln = (rem >> 3) & 63;
            int row = rt * 16 + (ln & 15);
            int col = kk * 32 + (ln >> 4) * 8;
            *(uint4*)(Dp + u) = *(const uint4*)&T[row * 256 + (col ^ ((row & 7) << 3))];
        }
        return;
    }
    if (y == 6 || y == 8) {                        // ---- bin_count (R or L)
        if (x >= NCH * BB) return;
        const float* KP = (y == 8) ? kptsL : kptsR;
        int* H = (y == 8) ? histL : hist;
        unsigned short* PR = (y == 8) ? prankL : prank;
        int chunk = x & 15, b = x >> 4;
        int* h = (int*)SMEM;
        short* sbin = (short*)(SMEM + NBIN * 4);
        for (int i = tid; i < NBIN; i += CHK) h[i] = 0;
        int m = chunk * CHK + tid;
        float2 p = ((const float2*)KP)[(size_t)b * MM + m];
        int bin = (int)p.y;
        sbin[tid] = (short)bin;
        __syncthreads();
        atomicAdd(&h[bin], 1);
        int r = 0;
        for (int t = 0; t < tid; ++t) r += (sbin[t] == bin);
        PR[(b << 12) + m] = (unsigned short)r;
        __syncthreads();
        for (int i = tid; i < NBIN; i += CHK)
            H[((size_t)b * NCH + chunk) * NBIN + i] = h[i];
        return;
    }
    // ---- y == 7: urmean (x<4) / Vsum zero (x==4)
    if (x < BB) {
        int b = x;
        float s = 0.f;
        for (int m = tid; m < MM; m += 256) s += kptsR[((size_t)b * MM + m) * 2 + 0];
#pragma unroll
        for (int off = 32; off; off >>= 1) s += __shfl_xor(s, off);
        float* sr = (float*)SMEM;
        int wave = tid >> 6, lane = tid & 63;
        if (lane == 0) sr[wave] = s;
        __syncthreads();
        if (tid == 0) Usum[b] = sr[0] + sr[1] + sr[2] + sr[3];
    } else if (x == BB) {
        for (int i = tid; i < BB * CC; i += 256) Vsum[i] = 0.f;
    }
}

// ================= MFMA projection + parallel bin place (R & L) ===============
// y=0..2: O = A @ W^T + b. y==3 (QKV launch, x<128): place block — x<64 places
// R (indices+UV, writes binStart), x in [64,128) places L (query sort indices).
template <bool OUT_BF16>
__global__ __launch_bounds__(256, 4) void proj_mfma_kernel(
    const unsigned short* __restrict__ A0, const unsigned short* __restrict__ A1,
    const unsigned short* __restrict__ A2, const unsigned short* __restrict__ Wpk,
    const float* __restrict__ b0, const float* __restrict__ b1, const float* __restrict__ b2,
    void* __restrict__ O0, void* __restrict__ O1, void* __restrict__ O2,
    float* __restrict__ Vsum,
    const int* __restrict__ hist, const int* __restrict__ histL,
    int* __restrict__ binStart,
    const float* __restrict__ kptsR, const float* __restrict__ kptsL,
    const unsigned short* __restrict__ prank, const unsigned short* __restrict__ prankL,
    unsigned short* __restrict__ sortedM, float2* __restrict__ sortedUV,
    unsigned short* __restrict__ sortedNL)
{
    __shared__ __align__(16) unsigned char SMEM[32768];   // W panel / bounce / sort
    const int tid = threadIdx.x, wid = tid >> 6, lane = tid & 63;
    const int y = blockIdx.y;

    if (y == 3) {                  // ---- place with local scan (128 parallel blocks)
        if (blockIdx.x >= 2 * NCH * BB) return;
        const int isL = blockIdx.x >= NCH * BB;
        const int xx = blockIdx.x & (NCH * BB - 1);
        const int b = xx >> 4, chunk = xx & 15;
        const int* H = isL ? histL : hist;
        int* h2 = (int*)SMEM;                      // [NCH][NBIN] 24576 B
        int* sc = (int*)(SMEM + 24576);            // [NBIN]
        for (int i = tid; i < NCH * NBIN; i += 256)
            h2[i] = H[(size_t)b * NCH * NBIN + i];
        __syncthreads();
        for (int v = tid; v < NBIN; v += 256) {
            int tot = 0;
#pragma unroll
            for (int c = 0; c < NCH; ++c) tot += h2[c * NBIN + v];
            sc[v] = tot;
        }
        __syncthreads();
        for (int off = 1; off < NBIN; off <<= 1) {
            int v1 = tid + 256;
            int t0 = (tid >= off) ? sc[tid - off] : 0;
            int t1 = (v1 < NBIN && v1 >= off) ? sc[v1 - off] : 0;
            __syncthreads();
            sc[tid] += t0;
            if (v1 < NBIN) sc[v1] += t1;
            __syncthreads();
        }
        if (!isL && chunk == 0) {
            for (int v = tid; v < NBIN; v += 256)
                binStart[b * (NBIN + 1) + v] = v ? sc[v - 1] : 0;
            if (tid == 0) binStart[b * (NBIN + 1) + NBIN] = sc[NBIN - 1];
        }
        int m = chunk * CHK + tid;
        float2 p = ((const float2*)(isL ? kptsL : kptsR))[(size_t)b * MM + m];
        int bin = (int)p.y;
        int ex = bin ? sc[bin - 1] : 0;
        for (int c = 0; c < chunk; ++c) ex += h2[c * NBIN + bin];
        int pos = ex + (isL ? prankL : prank)[(b << 12) + m];
        if (isL) {
            sortedNL[(b << 12) + pos] = (unsigned short)m;
        } else {
            sortedM[(b << 12) + pos] = (unsigned short)m;
            sortedUV[(b << 12) + pos] = p;
        }
        return;
    }

    const int lrow = lane & 15, lk = lane >> 4;
    const unsigned short* A = (y == 0) ? A0 : (y == 1) ? A1 : A2;
    const float* bias = (y == 0) ? b0 : (y == 1) ? b1 : b2;
    void* Out = (y == 0) ? O0 : (y == 1) ? O1 : O2;
    const unsigned short* W = Wpk + (size_t)y * 65536;

    const int bid = blockIdx.x;
    const int g = (bid >> 3) & 3;                    // colgroup (64 cols)
    const int rblk = (bid & 7) + ((bid >> 5) << 3);  // [0,128): same rblk -> same XCD
    const size_t rbase = (size_t)rblk * 128;
    const int rt0 = rblk * 8 + wid * 2;

    // stage this block's W panel (8 kk x 4 t x 1KB = 32KB) into LDS, linear
    unsigned short* Wl = (unsigned short*)SMEM;
#pragma unroll
    for (int i = 0; i < 8; ++i) {
        int kk = wid * 2 + (i >> 2), q = i & 3;
        gload16(W + (size_t)kk * 8192 + g * 2048 + q * 512 + lane * 8,
                Wl + kk * 2048 + q * 512 + lane * 8);
    }

    const unsigned short* Ap = A + (size_t)rt0 * 4096 + lane * 8;
    uint4 a[2][2];
    a[0][0] = *(const uint4*)(Ap);
    a[0][1] = *(const uint4*)(Ap + 4096);

    f32x4 acc[4][2];
#pragma unroll
    for (int t = 0; t < 4; ++t) {
        acc[t][0] = (f32x4){0.f, 0.f, 0.f, 0.f};
        acc[t][1] = (f32x4){0.f, 0.f, 0.f, 0.f};
    }

    asm volatile("s_waitcnt vmcnt(0)" ::: "memory");
    __syncthreads();                                 // W panel resident

#pragma unroll
    for (int kk = 0; kk < 8; ++kk) {
        const int cur = kk & 1, nxt = cur ^ 1;
        if (kk < 7) {
            a[nxt][0] = *(const uint4*)(Ap + (kk + 1) * 512);
            a[nxt][1] = *(const uint4*)(Ap + 4096 + (kk + 1) * 512);
        }
        bf16x8 af0 = asbf(a[cur][0]);
        bf16x8 af1 = asbf(a[cur][1]);
#pragma unroll
        for (int t = 0; t < 4; ++t) {
            bf16x8 wf = *(const bf16x8*)(Wl + kk * 2048 + t * 512 + lane * 8);
            acc[t][0] = __builtin_amdgcn_mfma_f32_16x16x32_bf16(af0, wf, acc[t][0], 0, 0, 0);
            acc[t][1] = __builtin_amdgcn_mfma_f32_16x16x32_bf16(af1, wf, acc[t][1], 0, 0, 0);
        }
    }

    // V column sums for the all-masked fallback path (QKV launch, y==2 only)
    if (Vsum != nullptr && y == 2) {
#pragma unroll
        for (int t = 0; t < 4; ++t) {
            int col = g * 64 + t * 16 + lrow;
            float vs = acc[t][0][0] + acc[t][0][1] + acc[t][0][2] + acc[t][0][3]
                     + acc[t][1][0] + acc[t][1][1] + acc[t][1][2] + acc[t][1][3];
            vs += __shfl_xor(vs, 16);
            vs += __shfl_xor(vs, 32);
            if (lk == 0)
                atomicAdd(&Vsum[(rblk >> 5) * CC + col], vs + 32.f * bias[col]);
        }
    }

    __syncthreads();                                 // done reading Wl; reuse as bounce
    if constexpr (OUT_BF16) {
        unsigned short* Bo = (unsigned short*)SMEM;  // [128][64]
#pragma unroll
        for (int t = 0; t < 4; ++t) {
            float bb = bias[g * 64 + t * 16 + lrow];
#pragma unroll
            for (int s = 0; s < 2; ++s)
#pragma unroll
                for (int rr = 0; rr < 4; ++rr) {
                    int row = wid * 32 + s * 16 + lk * 4 + rr;
                    Bo[row * 64 + t * 16 + lrow] = f2bf(acc[t][s][rr] + bb);
                }
        }
        __syncthreads();
        unsigned short* O = (unsigned short*)Out;
#pragma unroll
        for (int it = 0; it < 4; ++it) {
            int idx = it * 2048 + tid * 8;
            int row = idx >> 6, col = idx & 63;
            *(uint4*)(O + (rbase + row) * CC + g * 64 + col) = *(const uint4*)&Bo[idx];
        }
    } else {
        float* O = (float*)Out;
#pragma unroll
        for (int t = 0; t < 4; ++t) {
            float bb = bias[g * 64 + t * 16 + lrow];
#pragma unroll
            for (int s = 0; s < 2; ++s)
#pragma unroll
                for (int rr = 0; rr < 4; ++rr) {
                    int row = wid * 32 + s * 16 + lk * 4 + rr;
                    O[(rbase + row) * CC + g * 64 + t * 16 + lrow] = acc[t][s][rr] + bb;
                }
        }
    }
}

// packed-MT write offset for row bn, cols lane*4..lane*4+3
static __device__ __forceinline__ size_t mt_po(int bn, int lane) {
    return ((size_t)(bn >> 4)) * 4096 + (size_t)(lane >> 3) * 512
         + (size_t)(((lane >> 1) & 3) * 16 + (bn & 15)) * 8 + (lane & 1) * 4;
}

// ================= sparse attention: one wave per query row (vL-sorted) =======
__global__ __launch_bounds__(256) void attn_kernel(
    const unsigned short* __restrict__ Q, const unsigned short* __restrict__ K,
    const unsigned short* __restrict__ V,
    const float* __restrict__ kptsL, const unsigned short* __restrict__ sortedNL,
    const int* __restrict__ binStart, const unsigned short* __restrict__ sortedM,
    const float2* __restrict__ sortedUV,
    const float* __restrict__ Vsum, const float* __restrict__ Usum,
    unsigned short* __restrict__ Mpk, float* __restrict__ out1, float* __restrict__ out2)
{
    __shared__ unsigned short s_m[4][CAP];
    __shared__ float s_du[4][CAP];
    __shared__ float s_p[4][CAP];

    const int wid = threadIdx.x >> 6, lane = threadIdx.x & 63;
    const int bid = (blockIdx.x & 7) * 512 + (blockIdx.x >> 3);
    const int si = bid * 4 + wid;          // global sorted index
    const int b = si >> 12;
    const int bn = (b << 12) + sortedNL[si];

    const int gi = lane >> 4, c = lane & 15;
    float qf[16];
    {
        const unsigned short* Qr = Q + (size_t)bn * CC + c * 16;
#pragma unroll
        for (int j = 0; j < 4; ++j) {
            ushort4 t = *(const ushort4*)(Qr + j * 4);
            qf[j * 4 + 0] = bf2f(t.x); qf[j * 4 + 1] = bf2f(t.y);
            qf[j * 4 + 2] = bf2f(t.z); qf[j * 4 + 3] = bf2f(t.w);
        }
    }

    float2 kl = *(const float2*)(kptsL + (size_t)bn * 2);
    float uL = kl.x, vL = kl.y;

    int ifl = (int)vL;
    int v0 = max(0, ifl - 3), v1 = min(NBIN - 1, ifl + 3);
    int s = binStart[b * (NBIN + 1) + v0];
    int e = binStart[b * (NBIN + 1) + v1 + 1];

    int cnt = 0;
    for (int i0 = s; i0 < e; i0 += 64) {
        int i = i0 + lane;
        bool valid = false;
        float du = 0.f;
        int m = 0;
        if (i < e) {
            float2 uv = sortedUV[(b << 12) + i];
            m = sortedM[(b << 12) + i];
            du = uL - uv.x;
            float dv = fabsf(vL - uv.y);
            valid = (dv < 3.0f) && (du > 0.0f) && (du < 192.0f);
        }
        unsigned long long bal = __ballot(valid);
        int pos = cnt + __popcll(bal & ((1ull << lane) - 1ull));
        if (valid && pos < CAP) { s_m[wid][pos] = (unsigned short)m; s_du[wid][pos] = du; }
        cnt += __popcll(bal);
    }
    if (cnt > CAP) cnt = CAP;

    if (cnt == 0) {
        float4 vs = *(const float4*)(Vsum + b * CC + lane * 4);
        ushort4 o = make_ushort4(f2bf(vs.x * (1.f / MM)), f2bf(vs.y * (1.f / MM)),
                                 f2bf(vs.z * (1.f / MM)), f2bf(vs.w * (1.f / MM)));
        *(ushort4*)(Mpk + mt_po(bn, lane)) = o;
        if (lane == 0) { out1[bn] = uL - Usum[b] * (1.f / MM); out2[bn] = 0.f; }
        return;
    }

    const unsigned short* Kb = K + (((size_t)b) << 12) * CC;
    for (int i0 = 0; i0 < cnt; i0 += 4) {
        int i = i0 + gi;
        int m = s_m[wid][(i < cnt) ? i : 0];
        const unsigned short* Kr = Kb + (size_t)m * CC + c * 16;
        float d = 0.f;
#pragma unroll
        for (int j = 0; j < 4; ++j) {
            ushort4 t = *(const ushort4*)(Kr + j * 4);
            d += qf[j * 4 + 0] * bf2f(t.x) + qf[j * 4 + 1] * bf2f(t.y)
               + qf[j * 4 + 2] * bf2f(t.z) + qf[j * 4 + 3] * bf2f(t.w);
        }
        d += __shfl_xor(d, 8); d += __shfl_xor(d, 4);
        d += __shfl_xor(d, 2); d += __shfl_xor(d, 1);
        if (c == 0 && i < cnt) s_p[wid][i] = d;
    }

    const float NEG = -3.0e38f;
    float mx, ps, ds, inv;
    if (cnt <= 64) {                                  // common case: one slot
        float x0 = (lane < cnt) ? s_p[wid][lane] * 0.0625f : NEG;
        mx = x0;
#pragma unroll
        for (int off = 32; off; off >>= 1) mx = fmaxf(mx, __shfl_xor(mx, off));
        float p0 = (lane < cnt) ? __expf(x0 - mx) : 0.f;
        float d0 = (lane < cnt) ? s_du[wid][lane] : 0.f;
        ps = p0; ds = p0 * d0;
#pragma unroll
        for (int off = 32; off; off >>= 1) { ps += __shfl_xor(ps, off); ds += __shfl_xor(ds, off); }
        inv = 1.f / ps;
        if (lane < cnt) s_p[wid][lane] = p0 * inv;
    } else {
        float x0 = (lane < cnt) ? s_p[wid][lane] * 0.0625f : NEG;
        float x1 = (lane + 64 < cnt) ? s_p[wid][lane + 64] * 0.0625f : NEG;
        mx = fmaxf(x0, x1);
#pragma unroll
        for (int off = 32; off; off >>= 1) mx = fmaxf(mx, __shfl_xor(mx, off));
        float p0 = (lane < cnt) ? __expf(x0 - mx) : 0.f;
        float p1 = (lane + 64 < cnt) ? __expf(x1 - mx) : 0.f;
        float d0 = (lane < cnt) ? s_du[wid][lane] : 0.f;
        float d1 = (lane + 64 < cnt) ? s_du[wid][lane + 64] : 0.f;
        ps = p0 + p1; ds = p0 * d0 + p1 * d1;
#pragma unroll
        for (int off = 32; off; off >>= 1) { ps += __shfl_xor(ps, off); ds += __shfl_xor(ds, off); }
        inv = 1.f / ps;
        if (lane < cnt) s_p[wid][lane] = p0 * inv;
        if (lane + 64 < cnt) s_p[wid][lane + 64] = p1 * inv;
    }

    const unsigned short* Vb = V + (((size_t)b) << 12) * CC;
    float a0 = 0.f, a1 = 0.f, a2 = 0.f, a3 = 0.f;
    float e0 = 0.f, e1 = 0.f, e2 = 0.f, e3 = 0.f;
    int i = 0;
    for (; i + 1 < cnt; i += 2) {
        float w0 = s_p[wid][i], w1 = s_p[wid][i + 1];
        ushort4 va = *(const ushort4*)(Vb + (size_t)s_m[wid][i] * CC + lane * 4);
        ushort4 vb = *(const ushort4*)(Vb + (size_t)s_m[wid][i + 1] * CC + lane * 4);
        a0 += w0 * bf2f(va.x); a1 += w0 * bf2f(va.y);
        a2 += w0 * bf2f(va.z); a3 += w0 * bf2f(va.w);
        e0 += w1 * bf2f(vb.x); e1 += w1 * bf2f(vb.y);
        e2 += w1 * bf2f(vb.z); e3 += w1 * bf2f(vb.w);
    }
    if (i < cnt) {
        float w0 = s_p[wid][i];
        ushort4 va = *(const ushort4*)(Vb + (size_t)s_m[wid][i] * CC + lane * 4);
        a0 += w0 * bf2f(va.x); a1 += w0 * bf2f(va.y);
        a2 += w0 * bf2f(va.z); a3 += w0 * bf2f(va.w);
    }
    ushort4 o = make_ushort4(f2bf(a0 + e0), f2bf(a1 + e1), f2bf(a2 + e2), f2bf(a3 + e3));
    *(ushort4*)(Mpk + mt_po(bn, lane)) = o;
    if (lane == 0) { out1[bn] = ds * inv; out2[bn] = 1.f; }
}

extern "C" void kernel_launch(void* const* d_in, const int* in_sizes, int n_in,
                              void* d_out, int out_size, void* d_ws, size_t ws_size,
                              hipStream_t stream) {
    const float* nodes_L = (const float*)d_in[0];
    const float* nodes_R = (const float*)d_in[1];
    const float* kpts_L  = (const float*)d_in[2];
    const float* kpts_R  = (const float*)d_in[3];
    const float* Wq = (const float*)d_in[4];
    const float* bq = (const float*)d_in[5];
    const float* Wk = (const float*)d_in[6];
    const float* bk = (const float*)d_in[7];
    const float* Wv = (const float*)d_in[8];
    const float* bv = (const float*)d_in[9];
    const float* Wm = (const float*)d_in[10];
    const float* bm = (const float*)d_in[11];

    char* ws = (char*)d_ws;
    unsigned short* Wpk = (unsigned short*)ws; ws += (size_t)4 * 65536 * 2;
    unsigned short* Lpk = (unsigned short*)ws; ws += (size_t)BB * NN * CC * 2;
    unsigned short* Rpk = (unsigned short*)ws; ws += (size_t)BB * MM * CC * 2;
    unsigned short* Qp  = (unsigned short*)ws; ws += (size_t)BB * NN * CC * 2;
    unsigned short* Kp  = (unsigned short*)ws; ws += (size_t)BB * MM * CC * 2;
    unsigned short* Vp  = (unsigned short*)ws; ws += (size_t)BB * MM * CC * 2;
    unsigned short* Mpk = (unsigned short*)ws; ws += (size_t)BB * NN * CC * 2;
    float* Vsum = (float*)ws;        ws += (size_t)BB * CC * 4;
    float* Usum = (float*)ws;        ws += (size_t)BB * 4;
    float2* sortedUV = (float2*)ws;  ws += (size_t)BB * MM * 8;
    int* binStart = (int*)ws;        ws += (size_t)BB * (NBIN + 1) * 4;
    unsigned short* sortedM = (unsigned short*)ws; ws += (size_t)BB * MM * 2;
    int* hist = (int*)ws;            ws += (size_t)BB * NCH * NBIN * 4;
    unsigned short* prank = (unsigned short*)ws;   ws += (size_t)BB * MM * 2;
    int* histL = (int*)ws;           ws += (size_t)BB * NCH * NBIN * 4;
    unsigned short* prankL = (unsigned short*)ws;  ws += (size_t)BB * NN * 2;
    unsigned short* sortedNL = (unsigned short*)ws;

    float* out0 = (float*)d_out;
    float* out1 = out0 + (size_t)BB * NN * CC;
    float* out2 = out1 + (size_t)BB * NN;

    // 1) fused prep (y=8: query v-binning)
    prep_kernel<<<dim3(256, 9), dim3(256), 0, stream>>>(
        Wq, Wk, Wv, Wm, nodes_L, nodes_R, kpts_R, kpts_L,
        Wpk, Lpk, Rpk, hist, prank, histL, prankL, Vsum, Usum);

    // 2) fused Q/K/V projections (y=0..2) + parallel bin place R & L (y=3, x<128)
    proj_mfma_kernel<true><<<dim3(512, 4), dim3(256), 0, stream>>>(
        Lpk, Rpk, Rpk, Wpk, bq, bk, bv, Qp, Kp, Vp, Vsum,
        hist, histL, binStart, kpts_R, kpts_L, prank, prankL,
        sortedM, sortedUV, sortedNL);

    // 3) sparse attention in vL-sorted order (writes Mpk packed)
    attn_kernel<<<dim3(BB * NN / 4), dim3(256), 0, stream>>>(
        Qp, Kp, Vp, kpts_L, sortedNL, binStart, sortedM, sortedUV,
        Vsum, Usum, Mpk, out1, out2);

    // 4) final projection: out0 = Mpk @ Wm^T + bm (fp32 out)
    proj_mfma_kernel<false><<<dim3(512, 1), dim3(256), 0, stream>>>(
        Mpk, nullptr, nullptr, Wpk + 3 * 65536, bm, nullptr, nullptr,
        out0, nullptr, nullptr, nullptr,
        nullptr, nullptr, nullptr, nullptr, nullptr, nullptr, nullptr,
        nullptr, nullptr, nullptr);
}